// Round 15
// baseline (787.262 us; speedup 1.0000x reference)
//
#include <hip/hip_runtime.h>
#include <cstddef>

#define BB 8
#define NN 1024
#define CIN 40
#define CH 64
#define CC 128
#define COUT 9
#define KS 9
#define NL 10
#define HSTEP 0.1f

typedef __attribute__((ext_vector_type(8))) short bf16x8;
typedef __attribute__((ext_vector_type(4))) float f32x4;

__device__ __forceinline__ unsigned short f2bf(float f) {
    union { float f; unsigned u; } v;
    v.f = f;
    unsigned u = v.u;
    u += 0x7FFFu + ((u >> 16) & 1u);
    return (unsigned short)(u >> 16);
}
__device__ __forceinline__ float bf2f(unsigned short h) {
    union { unsigned u; float f; } v;
    v.u = ((unsigned)h) << 16;
    return v.f;
}

// packed-fragment address (chunk = 64 lanes x 8 shorts = 512 shorts):
// chunk=((lb*(R/32)+row>>5)*(KDv/32)+col>>5)*2+((row>>4)&1), lane=((col>>3)&3)*16+(row&15)
__device__ __forceinline__ size_t pk_addr(int lb, int row, int col, int R, int KDv) {
    int chunk = ((lb * (R / 32) + (row >> 5)) * (KDv / 32) + (col >> 5)) * 2 + ((row >> 4) & 1);
    int lane = ((col >> 3) & 3) * 16 + (row & 15);
    return ((size_t)chunk * 64 + lane) * 8 + (col & 7);
}

// ---------------- helpers ----------------
__device__ __forceinline__ float blockSum(float v, float* red) {
    int tid = threadIdx.x;
    red[tid] = v;
    __syncthreads();
    for (int s = 128; s > 0; s >>= 1) {
        if (tid < s) red[tid] += red[tid + s];
        __syncthreads();
    }
    float r = red[0];
    __syncthreads();
    return r;
}

__global__ __launch_bounds__(256) void k_zero(float* __restrict__ p, int n) {
    int i = blockIdx.x * 256 + threadIdx.x;
    if (i < n) p[i] = 0.f;
}

__global__ __launch_bounds__(256) void k_msum(const float* __restrict__ mask,
                                              float* __restrict__ msum) {
    __shared__ float red[256];
    int b = blockIdx.x, tid = threadIdx.x;
    float s = 0.f;
    for (int n = tid; n < NN; n += 256) s += mask[b * NN + n];
    s = blockSum(s, red);
    if (tid == 0) msum[b] = s;
}

// ---------------- conv weights -> packed fragments, k-major contraction, hi/lo ----------------
__global__ __launch_bounds__(256) void k_prep_wbf(const float* __restrict__ Win,
                                                  unsigned short* __restrict__ PKc_h,
                                                  unsigned short* __restrict__ PKc_l,
                                                  unsigned short* __restrict__ PKt_h,
                                                  unsigned short* __restrict__ PKt_l) {
    int idx = blockIdx.x * 256 + threadIdx.x;
    const int total = NL * 2 * CC * CH * KS;
    if (idx >= total) return;
    int k = idx % KS;
    int t = idx / KS;
    int i = t % CH;  t /= CH;
    int o = t % CC;  t /= CC;
    int lb = t;
    float v = Win[idx];
    unsigned short h = f2bf(v);
    unsigned short l = f2bf(v - bf2f(h));
    size_t ac = pk_addr(lb, o, k * 64 + i, CC, 576);
    size_t at = pk_addr(lb, i, (8 - k) * 128 + o, CH, 1152);
    PKc_h[ac] = h;
    PKc_l[ac] = l;
    PKt_h[at] = h;
    PKt_l[at] = l;
}

// bks[lb][o][k] = sum_i Win[lb][o][i][k] * Bias[lb][i]
__global__ __launch_bounds__(256) void k_prep_bks(const float* __restrict__ Win,
                                                  const float* __restrict__ Bias,
                                                  float* __restrict__ bks) {
    int idx = blockIdx.x * 256 + threadIdx.x;
    const int total = NL * 2 * CC * KS;
    if (idx >= total) return;
    int k = idx % KS;
    int t = idx / KS;
    int o = t % CC;
    int lb = t / CC;
    float s = 0.f;
    for (int i = 0; i < CH; ++i)
        s += Win[(((size_t)lb * CC + o) * CH + i) * KS + k] * Bias[lb * CH + i];
    bks[idx] = s;
}

// ---------------- open ----------------
__global__ __launch_bounds__(256) void k_open(const float* __restrict__ Zin,
                                              const float* __restrict__ mask,
                                              const float* __restrict__ Kop,
                                              float* __restrict__ Zcur) {
    int n = blockIdx.x * 256 + threadIdx.x;
    int c = blockIdx.y, b = blockIdx.z;
    float acc = 0.f;
    for (int i = 0; i < CIN; ++i)
        acc += Kop[c * CIN + i] * Zin[((size_t)b * CIN + i) * NN + n];
    Zcur[((size_t)b * CH + c) * NN + n] = acc * mask[b * NN + n];
}

// ---------------- Za ----------------
__global__ __launch_bounds__(256) void k_za(const float* __restrict__ Zcur,
                                            const float* __restrict__ mask,
                                            float* __restrict__ Za) {
    __shared__ float red[256];
    int c = blockIdx.x;  // 0..64
    int b = blockIdx.y;
    int tid = threadIdx.x;
    const float* m = mask + b * NN;
    float x[4], mv[4];
    if (c < CH) {
        const float* src = Zcur + ((size_t)b * CH + c) * NN;
#pragma unroll
        for (int j = 0; j < 4; ++j) { int n = tid * 4 + j; x[j] = src[n]; mv[j] = m[n]; }
    } else {
#pragma unroll
        for (int j = 0; j < 4; ++j) { int n = tid * 4 + j; mv[j] = m[n]; x[j] = 0.5f * ((float)n / 1023.f) * mv[j]; }
    }
    float sm = 0.f, sxm = 0.f;
#pragma unroll
    for (int j = 0; j < 4; ++j) { sm += mv[j]; sxm += x[j] * mv[j]; }
    float msum = blockSum(sm, red);
    float xm = blockSum(sxm, red);
    if (c < CH) {
        float mean = xm / msum;
        float ss = 0.f;
#pragma unroll
        for (int j = 0; j < 4; ++j) { x[j] -= mean * mv[j]; ss += x[j] * x[j]; }
        ss = blockSum(ss, red);
        float sc = rsqrtf(ss / msum + 1e-4f);
#pragma unroll
        for (int j = 0; j < 4; ++j) x[j] *= sc;
    }
    float ps = 0.f;
#pragma unroll
    for (int j = 0; j < 4; ++j) ps += x[j];
    float pm = blockSum(ps, red) / (float)NN;
    float* dst = Za + ((size_t)b * 65 + c) * NN;
#pragma unroll
    for (int j = 0; j < 4; ++j) dst[tid * 4 + j] = x[j] - pm;
}

// ---------------- Gram + W: local n2, writes packed bf16 W + atomic fp32 Wsum ----------------
__global__ __launch_bounds__(256) void k_gramW(const float* __restrict__ Za,
                                               const float* __restrict__ mask,
                                               unsigned short* __restrict__ Wpk,
                                               float* __restrict__ Wsum) {
    __shared__ float As[65][68];
    __shared__ float Bs2[65][68];
    __shared__ unsigned short wt[64][72];
    __shared__ float csred[16][64];
    __shared__ float n2is[64], n2js[64];
    int i0 = blockIdx.x * 64, j0 = blockIdx.y * 64, b = blockIdx.z;
    int tid = threadIdx.x;
    for (int e = tid; e < 65 * 64; e += 256) {
        int c = e >> 6, t = e & 63;
        const float* src = Za + ((size_t)b * 65 + c) * NN;
        As[c][t] = src[i0 + t];
        Bs2[c][t] = src[j0 + t];
    }
    __syncthreads();
    if (tid < 64) {
        float s = 0.f;
        for (int c = 0; c < 65; ++c) { float v = As[c][tid]; s += v * v; }
        n2is[tid] = s;
    } else if (tid < 128) {
        int t = tid - 64;
        float s = 0.f;
        for (int c = 0; c < 65; ++c) { float v = Bs2[c][t]; s += v * v; }
        n2js[t] = s;
    }
    __syncthreads();
    int tx = tid & 15, ty = tid >> 4;
    float acc[4][4] = {};
    for (int c = 0; c < 65; ++c) {
        float a[4];
#pragma unroll
        for (int q = 0; q < 4; ++q) a[q] = As[c][ty * 4 + q];
        float bv[4];
        *reinterpret_cast<float4*>(bv) = *reinterpret_cast<const float4*>(&Bs2[c][tx * 4]);
#pragma unroll
        for (int q = 0; q < 4; ++q)
#pragma unroll
            for (int r = 0; r < 4; ++r) acc[q][r] += a[q] * bv[r];
    }
    const float* m = mask + b * NN;
    float csacc[4] = {0.f, 0.f, 0.f, 0.f};
    for (int q = 0; q < 4; ++q) {
        int i = i0 + ty * 4 + q;
        float n2i = n2is[ty * 4 + q], mi = m[i];
#pragma unroll
        for (int r = 0; r < 4; ++r) {
            int j = j0 + tx * 4 + r;
            float D = n2i + n2js[tx * 4 + r] - 2.f * acc[q][r];
            D *= (3.f / 65.f);
            D = fmaxf(D, 0.f);
            float dist = (D > 0.f) ? sqrtf(D) : 0.f;
            float mmv = mi * m[j];
            float res = expf(-dist * mmv) * mmv;
            wt[ty * 4 + q][tx * 4 + r] = f2bf(res);
            csacc[r] += res;
        }
    }
#pragma unroll
    for (int r = 0; r < 4; ++r) csred[ty][tx * 4 + r] = csacc[r];
    __syncthreads();
    for (int s = 8; s > 0; s >>= 1) {
        if (ty < s) {
#pragma unroll
            for (int r = 0; r < 4; ++r) csred[ty][tx * 4 + r] += csred[ty + s][tx * 4 + r];
        }
        __syncthreads();
    }
    if (ty == 0) {
#pragma unroll
        for (int r = 0; r < 4; ++r)
            atomicAdd(&Wsum[b * NN + j0 + tx * 4 + r], csred[0][tx * 4 + r]);
    }
    for (int e = tid; e < 512; e += 256) {
        int li = e >> 3, ljb = (e & 7) * 8;
        int row = i0 + li, col = j0 + ljb;
        int chunk = ((b * 32 + (row >> 5)) * 32 + (col >> 5)) * 2 + ((row >> 4) & 1);
        int lane2 = ((col >> 3) & 3) * 16 + (row & 15);
        unsigned short* dp = Wpk + ((size_t)chunk * 64 + lane2) * 8;
        *reinterpret_cast<ushort4*>(dp) = *reinterpret_cast<ushort4*>(&wt[li][ljb]);
        *reinterpret_cast<ushort4*>(dp + 4) = *reinterpret_cast<ushort4*>(&wt[li][ljb + 4]);
    }
}

// ---------------- conv1 (k-major MFMA): block 64o x 64n, y=(br,o_half) ----------------
// br==0 emits meanP0[b][c][nt16] masked row-partials; br==1 emits C1pk packed bf16.
__global__ __launch_bounds__(256) void k_conv1_mfma(const float* __restrict__ Zcur,
                                                    const unsigned short* __restrict__ Wh,
                                                    const unsigned short* __restrict__ Wl,
                                                    const float* __restrict__ bksl,
                                                    const float* __restrict__ mask,
                                                    float* __restrict__ C0,
                                                    float* __restrict__ C1,
                                                    unsigned short* __restrict__ C1pk,
                                                    float* __restrict__ meanP0) {
    __shared__ __align__(16) unsigned short xh[80][64];
    __shared__ __align__(16) unsigned short xl[80][64];
    __shared__ float rs[64][2];
    int n0 = blockIdx.x * 64;
    int y = blockIdx.y;
    int b = blockIdx.z;
    int br = y >> 1, half = y & 1;
    int tid = threadIdx.x;
    const float* Xb = Zcur + (size_t)b * CH * NN;

    for (int e = tid; e < 64 * 20; e += 256) {
        int i = e / 20, t = e - i * 20;
        int gn = n0 + t * 4 - 4;
        float4 v = make_float4(0.f, 0.f, 0.f, 0.f);
        if (gn >= 0 && gn + 3 < NN) v = *reinterpret_cast<const float4*>(&Xb[(size_t)i * NN + gn]);
        float vv[4] = {v.x, v.y, v.z, v.w};
#pragma unroll
        for (int j = 0; j < 4; ++j) {
            int row = t * 4 + j;
            int col = i ^ ((row & 7) << 3);
            unsigned short h = f2bf(vv[j]);
            xh[row][col] = h;
            xl[row][col] = f2bf(vv[j] - bf2f(h));
        }
    }
    __syncthreads();

    int wid = tid >> 6, lane = tid & 63;
    int wo = (wid >> 1) * 32, wn = (wid & 1) * 32;
    int r = lane & 15, g = lane >> 4;
    int r32 = half * 2 + (wid >> 1);
    size_t brOff = (size_t)br * (CC / 32) * (576 / 32) * 1024;

    f32x4 acc[2][2] = {};
#pragma unroll 3
    for (int q = 0; q < 18; ++q) {
        int k = q >> 1, s = q & 1;
        size_t widx = brOff + ((size_t)(r32 * 18 + q)) * 1024 + lane * 8;
        bf16x8 ah[2], al[2];
        ah[0] = *reinterpret_cast<const bf16x8*>(&Wh[widx]);
        ah[1] = *reinterpret_cast<const bf16x8*>(&Wh[widx + 512]);
        al[0] = *reinterpret_cast<const bf16x8*>(&Wl[widx]);
        al[1] = *reinterpret_cast<const bf16x8*>(&Wl[widx + 512]);
        bf16x8 bh[2], bl[2];
#pragma unroll
        for (int fn = 0; fn < 2; ++fn) {
            int row = wn + fn * 16 + r + k;
            int chs = (s * 32 + g * 8) ^ ((row & 7) << 3);
            bh[fn] = *reinterpret_cast<const bf16x8*>(&xh[row][chs]);
            bl[fn] = *reinterpret_cast<const bf16x8*>(&xl[row][chs]);
        }
#pragma unroll
        for (int fc = 0; fc < 2; ++fc)
#pragma unroll
            for (int fn = 0; fn < 2; ++fn) {
                acc[fc][fn] = __builtin_amdgcn_mfma_f32_16x16x32_bf16(ah[fc], bh[fn], acc[fc][fn], 0, 0, 0);
                acc[fc][fn] = __builtin_amdgcn_mfma_f32_16x16x32_bf16(al[fc], bh[fn], acc[fc][fn], 0, 0, 0);
                acc[fc][fn] = __builtin_amdgcn_mfma_f32_16x16x32_bf16(ah[fc], bl[fn], acc[fc][fn], 0, 0, 0);
            }
    }

    const float* mkB = mask + b * NN;
    float* Outp = (br ? C1 : C0) + ((size_t)b * CC + half * 64) * NN;
    const float* bo_base = bksl + (br * CC + half * 64) * KS;
    float p[2][4] = {};
#pragma unroll
    for (int fc = 0; fc < 2; ++fc) {
#pragma unroll
        for (int fn = 0; fn < 2; ++fn) {
            int n = n0 + wn + fn * 16 + r;
#pragma unroll
            for (int rr = 0; rr < 4; ++rr) {
                int oo = wo + fc * 16 + 4 * g + rr;
                float v = acc[fc][fn][rr];
                const float* bo = bo_base + oo * KS;
                float bias = 0.f;
#pragma unroll
                for (int k = 0; k < KS; ++k) {
                    int nn2 = n + k - 4;
                    if (nn2 >= 0 && nn2 < NN) bias += bo[k];
                }
                v += bias;
                if (br == 0) {
                    v *= mkB[n];
                    p[fc][rr] += v * mkB[n];
                }
                Outp[(size_t)oo * NN + n] = v;
                if (br == 1) {
                    int cg = half * 64 + oo;
                    int chunk = ((b * 4 + (cg >> 5)) * 32 + (n >> 5)) * 2 + ((cg >> 4) & 1);
                    int lane2 = ((n >> 3) & 3) * 16 + (cg & 15);
                    C1pk[((size_t)chunk * 64 + lane2) * 8 + (n & 7)] = f2bf(v);
                }
            }
        }
    }
    if (br == 0) {
#pragma unroll
        for (int fc = 0; fc < 2; ++fc)
#pragma unroll
            for (int rr = 0; rr < 4; ++rr) {
                float v = p[fc][rr];
                v += __shfl_xor(v, 1); v += __shfl_xor(v, 2);
                v += __shfl_xor(v, 4); v += __shfl_xor(v, 8);
                if (r == 0) rs[wo + fc * 16 + 4 * g + rr][wid & 1] = v;
            }
        __syncthreads();
        if (tid < 64)
            meanP0[((size_t)b * CC + half * 64 + tid) * 16 + blockIdx.x] = rs[tid][0] + rs[tid][1];
    }
}

// ---------------- fused CC matL, 16-wide n-tiles ----------------
// grid (NN/16, 1, BB*2); block 64c x 16n; waves: kh=wid>>1 K-half, ch=wid&1 c-half.
// A1 = (C1*Wsum - acc)*mask ; emits meanP1[b][c][nt16] (64 partials/row).
__global__ __launch_bounds__(256) void k_matL_cc(const unsigned short* __restrict__ C1pk,
                                                 const unsigned short* __restrict__ Wpk,
                                                 const float* __restrict__ C1,
                                                 const float* __restrict__ Wsum,
                                                 const float* __restrict__ mask,
                                                 float* __restrict__ A1,
                                                 float* __restrict__ meanP1) {
    __shared__ float red2[2][32][17];
    int nt16 = blockIdx.x;
    int nt32 = nt16 >> 1, fsel = nt16 & 1;
    int b = blockIdx.z >> 1, chalf = blockIdx.z & 1;
    int c0 = chalf * 64;
    int tid = threadIdx.x;
    int wid = tid >> 6, lane = tid & 63;
    int kh = wid >> 1, ch = wid & 1;
    int r = lane & 15, g = lane >> 4;
    int ct = chalf * 2 + ch;
    const unsigned short* Xb = C1pk + ((size_t)(b * 4 + ct)) * 32768 + (size_t)lane * 8;
    const unsigned short* Wb = Wpk + ((size_t)(b * 32 + nt32)) * 32768 + (size_t)fsel * 512 + (size_t)lane * 8;

    f32x4 acc[2] = {};
#pragma unroll 4
    for (int ms = kh * 16; ms < kh * 16 + 16; ++ms) {
        bf16x8 a0 = *reinterpret_cast<const bf16x8*>(&Xb[(size_t)ms * 1024]);
        bf16x8 a1 = *reinterpret_cast<const bf16x8*>(&Xb[(size_t)ms * 1024 + 512]);
        bf16x8 w = *reinterpret_cast<const bf16x8*>(&Wb[(size_t)ms * 1024]);
        acc[0] = __builtin_amdgcn_mfma_f32_16x16x32_bf16(a0, w, acc[0], 0, 0, 0);
        acc[1] = __builtin_amdgcn_mfma_f32_16x16x32_bf16(a1, w, acc[1], 0, 0, 0);
    }
    if (kh == 1) {
#pragma unroll
        for (int fc = 0; fc < 2; ++fc)
#pragma unroll
            for (int rr = 0; rr < 4; ++rr)
                red2[ch][fc * 16 + 4 * g + rr][r] = acc[fc][rr];
    }
    __syncthreads();
    if (kh == 0) {
        const float* C1b = C1 + (size_t)b * CC * NN;
        float* A1b = A1 + (size_t)b * CC * NN;
        const float* mk = mask + b * NN;
        const float* wsB = Wsum + b * NN;
        int ncol = nt16 * 16 + r;
        float mkv = mk[ncol], wsv = wsB[ncol];
        float p[2][4] = {};
#pragma unroll
        for (int fc = 0; fc < 2; ++fc)
#pragma unroll
            for (int rr = 0; rr < 4; ++rr) {
                int crow = c0 + ch * 32 + fc * 16 + 4 * g + rr;
                float v = acc[fc][rr] + red2[ch][fc * 16 + 4 * g + rr][r];
                float y = C1b[(size_t)crow * NN + ncol] * wsv - v;
                float res = y * mkv;
                A1b[(size_t)crow * NN + ncol] = res;
                p[fc][rr] += res * mkv;
            }
#pragma unroll
        for (int fc = 0; fc < 2; ++fc)
#pragma unroll
            for (int rr = 0; rr < 4; ++rr) {
                float v = p[fc][rr];
                v += __shfl_xor(v, 1); v += __shfl_xor(v, 2);
                v += __shfl_xor(v, 4); v += __shfl_xor(v, 8);
                if (r == 0)
                    meanP1[((size_t)b * CC + c0 + ch * 32 + fc * 16 + 4 * g + rr) * 64 + nt16] = v;
            }
    }
}

// ---------------- conv1T (k-major MFMA): block 64i x 32n, y=br; in-block split-K ----------------
// Colnorm fully local; meanA assembled from meanP0/meanP1 partials + msum.
// br==1 additionally writes T1p packed bf16.
__global__ __launch_bounds__(256) void k_convT_mfma(const float* __restrict__ C0,
                                                    const float* __restrict__ A1,
                                                    const unsigned short* __restrict__ Wh,
                                                    const unsigned short* __restrict__ Wl,
                                                    const float* __restrict__ mask,
                                                    const float* __restrict__ meanP0,
                                                    const float* __restrict__ meanP1,
                                                    const float* __restrict__ msum,
                                                    float* __restrict__ T0,
                                                    float* __restrict__ T1p,
                                                    unsigned short* __restrict__ T1pk) {
    __shared__ float fs[48][132];
    __shared__ __align__(16) unsigned short xh[48][128];
    __shared__ __align__(16) unsigned short xl[48][128];
    __shared__ float red2[2][32][33];
    __shared__ float ps[48][4];
    __shared__ float invc[48];
    __shared__ float meB_sh[128];
    int n0 = blockIdx.x * 32;
    int br = blockIdx.y;
    int b = blockIdx.z;
    int tid = threadIdx.x;
    const float* Xb = (br ? A1 : C0) + (size_t)b * CC * NN;
    const float* mkB = mask + b * NN;

    if (tid < 128) {
        float s = 0.f;
        if (br == 0) {
            const float* mp = meanP0 + ((size_t)b * CC + tid) * 16;
#pragma unroll
            for (int t = 0; t < 16; ++t) s += mp[t];
        } else {
            const float* mp = meanP1 + ((size_t)b * CC + tid) * 64;
#pragma unroll
            for (int t = 0; t < 64; ++t) s += mp[t];
        }
        meB_sh[tid] = s / msum[b];
    }
    __syncthreads();

    // pass 1: stage raw (x - mean)*mask (fp32)
    for (int e = tid; e < 128 * 12; e += 256) {
        int i = e / 12, t = e - i * 12;
        int gn = n0 + t * 4 - 4;
        float4 v = make_float4(0.f, 0.f, 0.f, 0.f);
        if (gn >= 0 && gn + 3 < NN) {
            v = *reinterpret_cast<const float4*>(&Xb[(size_t)i * NN + gn]);
            float me = meB_sh[i];
            float4 mk = *reinterpret_cast<const float4*>(&mkB[gn]);
            v.x = (v.x - me) * mk.x;
            v.y = (v.y - me) * mk.y;
            v.z = (v.z - me) * mk.z;
            v.w = (v.w - me) * mk.w;
        }
        fs[t * 4 + 0][i] = v.x;
        fs[t * 4 + 1][i] = v.y;
        fs[t * 4 + 2][i] = v.z;
        fs[t * 4 + 3][i] = v.w;
    }
    __syncthreads();
    // pass 2: per-column sums over 128 channels -> inv
    if (tid < 192) {
        int row = tid % 48, seg = tid / 48;
        float ss = 0.f;
#pragma unroll
        for (int i = 0; i < 32; ++i) { float v = fs[row][seg * 32 + i]; ss += v * v; }
        ps[row][seg] = ss;
    }
    __syncthreads();
    if (tid < 48) invc[tid] = rsqrtf(ps[tid][0] + ps[tid][1] + ps[tid][2] + ps[tid][3] + 0.001f);
    __syncthreads();
    // pass 3: relu(v*inv), hi/lo pack with XOR swizzle
    for (int e = tid; e < 128 * 12; e += 256) {
        int i = e / 12, t = e - i * 12;
#pragma unroll
        for (int j = 0; j < 4; ++j) {
            int row = t * 4 + j;
            float v = fmaxf(fs[row][i] * invc[row], 0.f);
            int col = i ^ ((row & 7) << 3);
            unsigned short h = f2bf(v);
            xh[row][col] = h;
            xl[row][col] = f2bf(v - bf2f(h));
        }
    }
    __syncthreads();

    int wid = tid >> 6, lane = tid & 63;
    int i32 = wid & 1, kh = wid >> 1;
    int r = lane & 15, g = lane >> 4;
    size_t brW = (size_t)br * (CH / 32) * (1152 / 32) * 1024;

    f32x4 acc[2][2] = {};
#pragma unroll 3
    for (int t = 0; t < 18; ++t) {
        int k = t >> 1, s = kh * 2 + (t & 1);
        int q32 = k * 4 + s;
        size_t widx = brW + ((size_t)(i32 * 36 + q32)) * 1024 + lane * 8;
        bf16x8 ah[2], al[2];
        ah[0] = *reinterpret_cast<const bf16x8*>(&Wh[widx]);
        ah[1] = *reinterpret_cast<const bf16x8*>(&Wh[widx + 512]);
        al[0] = *reinterpret_cast<const bf16x8*>(&Wl[widx]);
        al[1] = *reinterpret_cast<const bf16x8*>(&Wl[widx + 512]);
        bf16x8 bh[2], bl[2];
#pragma unroll
        for (int fn = 0; fn < 2; ++fn) {
            int row = fn * 16 + r + k;
            int chs = (s * 32 + g * 8) ^ ((row & 7) << 3);
            bh[fn] = *reinterpret_cast<const bf16x8*>(&xh[row][chs]);
            bl[fn] = *reinterpret_cast<const bf16x8*>(&xl[row][chs]);
        }
#pragma unroll
        for (int fc = 0; fc < 2; ++fc)
#pragma unroll
            for (int fn = 0; fn < 2; ++fn) {
                acc[fc][fn] = __builtin_amdgcn_mfma_f32_16x16x32_bf16(ah[fc], bh[fn], acc[fc][fn], 0, 0, 0);
                acc[fc][fn] = __builtin_amdgcn_mfma_f32_16x16x32_bf16(al[fc], bh[fn], acc[fc][fn], 0, 0, 0);
                acc[fc][fn] = __builtin_amdgcn_mfma_f32_16x16x32_bf16(ah[fc], bl[fn], acc[fc][fn], 0, 0, 0);
            }
    }

    if (kh == 1) {
#pragma unroll
        for (int fc = 0; fc < 2; ++fc)
#pragma unroll
            for (int fn = 0; fn < 2; ++fn)
#pragma unroll
                for (int rr = 0; rr < 4; ++rr)
                    red2[i32][fc * 16 + 4 * g + rr][fn * 16 + r] = acc[fc][fn][rr];
    }
    __syncthreads();
    if (kh == 0) {
        float* Outp = (br ? T1p : T0) + (size_t)b * CH * NN;
#pragma unroll
        for (int fc = 0; fc < 2; ++fc)
#pragma unroll
            for (int fn = 0; fn < 2; ++fn) {
                int n = n0 + fn * 16 + r;
#pragma unroll
                for (int rr = 0; rr < 4; ++rr) {
                    int irow = fc * 16 + 4 * g + rr;
                    float v = acc[fc][fn][rr] + red2[i32][irow][fn * 16 + r];
                    Outp[(size_t)(i32 * 32 + irow) * NN + n] = v;
                    if (br == 1) {
                        int cg = i32 * 32 + irow;
                        int chunk = ((b * 2 + (cg >> 5)) * 32 + (n >> 5)) * 2 + ((cg >> 4) & 1);
                        int lane2 = ((n >> 3) & 3) * 16 + (cg & 15);
                        T1pk[((size_t)chunk * 64 + lane2) * 8 + (n & 7)] = f2bf(v);
                    }
                }
            }
    }
}

// ---------------- fused CH matL, 16-wide n-tiles ----------------
// grid (NN/16, 1, BB); block 64c x 16n; waves: kh x c-half.
__global__ __launch_bounds__(256) void k_matL_ch(const unsigned short* __restrict__ T1pk,
                                                 const unsigned short* __restrict__ Wpk,
                                                 const float* __restrict__ T1p,
                                                 const float* __restrict__ Wsum,
                                                 const float* __restrict__ mask,
                                                 const float* __restrict__ T0,
                                                 float* __restrict__ Zcur) {
    __shared__ float red2[2][32][17];
    int nt16 = blockIdx.x;
    int nt32 = nt16 >> 1, fsel = nt16 & 1;
    int b = blockIdx.z;
    int tid = threadIdx.x;
    int wid = tid >> 6, lane = tid & 63;
    int kh = wid >> 1, ch = wid & 1;
    int r = lane & 15, g = lane >> 4;
    const unsigned short* Xb = T1pk + ((size_t)(b * 2 + ch)) * 32768 + (size_t)lane * 8;
    const unsigned short* Wb = Wpk + ((size_t)(b * 32 + nt32)) * 32768 + (size_t)fsel * 512 + (size_t)lane * 8;

    f32x4 acc[2] = {};
#pragma unroll 4
    for (int ms = kh * 16; ms < kh * 16 + 16; ++ms) {
        bf16x8 a0 = *reinterpret_cast<const bf16x8*>(&Xb[(size_t)ms * 1024]);
        bf16x8 a1 = *reinterpret_cast<const bf16x8*>(&Xb[(size_t)ms * 1024 + 512]);
        bf16x8 w = *reinterpret_cast<const bf16x8*>(&Wb[(size_t)ms * 1024]);
        acc[0] = __builtin_amdgcn_mfma_f32_16x16x32_bf16(a0, w, acc[0], 0, 0, 0);
        acc[1] = __builtin_amdgcn_mfma_f32_16x16x32_bf16(a1, w, acc[1], 0, 0, 0);
    }
    if (kh == 1) {
#pragma unroll
        for (int fc = 0; fc < 2; ++fc)
#pragma unroll
            for (int rr = 0; rr < 4; ++rr)
                red2[ch][fc * 16 + 4 * g + rr][r] = acc[fc][rr];
    }
    __syncthreads();
    if (kh == 0) {
        const float* T1b = T1p + (size_t)b * CH * NN;
        const float* T0b = T0 + (size_t)b * CH * NN;
        float* Zb = Zcur + (size_t)b * CH * NN;
        const float* mk = mask + b * NN;
        const float* wsB = Wsum + b * NN;
        int ncol = nt16 * 16 + r;
        float mkv = mk[ncol], wsv = wsB[ncol];
#pragma unroll
        for (int fc = 0; fc < 2; ++fc)
#pragma unroll
            for (int rr = 0; rr < 4; ++rr) {
                int crow = ch * 32 + fc * 16 + 4 * g + rr;
                float v = acc[fc][rr] + red2[ch][fc * 16 + 4 * g + rr][r];
                float y = T1b[(size_t)crow * NN + ncol] * wsv - v;
                size_t zi = (size_t)crow * NN + ncol;
                Zb[zi] = Zb[zi] - HSTEP * mkv * (T0b[zi] + y);
            }
    }
}

// ---------------- close ----------------
__global__ __launch_bounds__(256) void k_close(const float* __restrict__ Zcur,
                                               const float* __restrict__ Kcl,
                                               const float* __restrict__ mask,
                                               float* __restrict__ Zout) {
    __shared__ float red[4][64][COUT];
    int tid = threadIdx.x;
    int nl = tid & 63, cg = tid >> 6;
    int n = blockIdx.x * 64 + nl;
    int b = blockIdx.y;
    float acc[COUT] = {};
#pragma unroll
    for (int cc = 0; cc < 16; ++cc) {
        int c = cg * 16 + cc;
        float zv = Zcur[((size_t)b * CH + c) * NN + n];
#pragma unroll
        for (int o = 0; o < COUT; ++o) acc[o] += Kcl[o * CH + c] * zv;
    }
#pragma unroll
    for (int o = 0; o < COUT; ++o) red[cg][nl][o] = acc[o];
    __syncthreads();
    if (cg == 0) {
        float mv = mask[b * NN + n];
#pragma unroll
        for (int o = 0; o < COUT; ++o) {
            float s = red[0][nl][o] + red[1][nl][o] + red[2][nl][o] + red[3][nl][o];
            Zout[((size_t)b * COUT + o) * NN + n] = s * mv;
        }
    }
}

// ---------------- center3 ----------------
__global__ __launch_bounds__(256) void k_center3(const float* __restrict__ Zout, float* __restrict__ Zc3) {
    __shared__ float red[256];
    int c = blockIdx.x, b = blockIdx.y, tid = threadIdx.x;
    const float* src = Zout + ((size_t)b * COUT + c) * NN;
    float s = 0.f;
    for (int n = tid; n < NN; n += 256) s += src[n];
    float mean = blockSum(s, red) / (float)NN;
    float* dst = Zc3 + ((size_t)b * COUT + c) * NN;
    for (int n = tid; n < NN; n += 256) dst[n] = src[n] - mean;
}

// ---------------- final pairwise distances ----------------
__global__ __launch_bounds__(256) void k_dist(const float* __restrict__ Zc3,
                                              float* __restrict__ dout) {
    __shared__ float Ai[3][64], Aj[3][64], ni[64], nj[64];
    int bg = blockIdx.z;
    int b = bg / 3, g = bg - 3 * b;
    int i0 = blockIdx.x * 64, j0 = blockIdx.y * 64;
    int tid = threadIdx.x;
    for (int e = tid; e < 192; e += 256) {
        int c = e / 64, t = e - c * 64;
        Ai[c][t] = Zc3[((size_t)b * COUT + g * 3 + c) * NN + i0 + t];
    }
    for (int e = tid; e < 192; e += 256) {
        int c = e / 64, t = e - c * 64;
        Aj[c][t] = Zc3[((size_t)b * COUT + g * 3 + c) * NN + j0 + t];
    }
    __syncthreads();
    if (tid < 64) {
        ni[tid] = Ai[0][tid] * Ai[0][tid] + Ai[1][tid] * Ai[1][tid] + Ai[2][tid] * Ai[2][tid];
    } else if (tid < 128) {
        int t = tid - 64;
        nj[t] = Aj[0][t] * Aj[0][t] + Aj[1][t] * Aj[1][t] + Aj[2][t] * Aj[2][t];
    }
    __syncthreads();
    int tx = tid & 15, ty = tid >> 4;
    for (int q = 0; q < 4; ++q) {
        int i = ty * 4 + q;
        float a0 = Ai[0][i], a1 = Ai[1][i], a2 = Ai[2][i], n2i = ni[i];
        float res[4];
#pragma unroll
        for (int r = 0; r < 4; ++r) {
            int j = tx * 4 + r;
            float D = n2i + nj[j] - 2.f * (a0 * Aj[0][j] + a1 * Aj[1][j] + a2 * Aj[2][j]);
            D = fmaxf(D, 0.f);
            res[r] = (D > 0.f) ? sqrtf(D) : 0.f;
        }
        *reinterpret_cast<float4*>(&dout[(((size_t)b * 3 + g) * NN + i0 + i) * NN + j0 + tx * 4]) =
            *reinterpret_cast<float4*>(res);
    }
}

// ---------------- driver ----------------
extern "C" void kernel_launch(void* const* d_in, const int* in_sizes, int n_in,
                              void* d_out, int out_size, void* d_ws, size_t ws_size,
                              hipStream_t stream) {
    (void)in_sizes; (void)n_in; (void)out_size; (void)ws_size;
    const float* Zin  = (const float*)d_in[0];
    const float* mask = (const float*)d_in[1];
    const float* Kop  = (const float*)d_in[2];
    const float* Kcl  = (const float*)d_in[3];
    const float* Win  = (const float*)d_in[4];
    const float* Bias = (const float*)d_in[5];
    float* out = (float*)d_out;
    float* ws = (float*)d_ws;

    size_t off = 0;
    float* Zcur = ws + off;  off += (size_t)BB * CH * NN;
    float* C0   = ws + off;  off += (size_t)BB * CC * NN;
    float* C1   = ws + off;  off += (size_t)BB * CC * NN;
    float* A1   = ws + off;  off += (size_t)BB * CC * NN;
    float* T0   = ws + off;  off += (size_t)BB * CH * NN;
    float* T1p  = ws + off;  off += (size_t)BB * CH * NN;
    float* Za   = ws + off;  off += (size_t)BB * 65 * NN;
    float* Wsum = ws + off;  off += (size_t)BB * NN;
    float* bks  = ws + off;  off += (size_t)NL * 2 * CC * KS;
    float* Zc3  = ws + off;  off += (size_t)BB * COUT * NN;
    float* meanP0 = ws + off; off += (size_t)BB * CC * 16;
    float* meanP1 = ws + off; off += (size_t)BB * CC * 64;
    float* msum = ws + off;  off += (size_t)BB;

    // Scratch in the (as-yet-unwritten) dists region of d_out (25,165,824 floats):
    unsigned short* Wpk2  = (unsigned short*)(out + (size_t)4194304);    // [.. 8,388,608)
    unsigned short* C1pk  = (unsigned short*)(out + (size_t)8388608);    // 1,048,576 shorts
    unsigned short* T1pk  = (unsigned short*)(out + (size_t)8912896);    // 524,288 shorts
    unsigned short* PKc_h = (unsigned short*)(out + (size_t)14680064);
    unsigned short* PKc_l = (unsigned short*)(out + (size_t)15417344);
    unsigned short* PKt_h = (unsigned short*)(out + (size_t)16154624);
    unsigned short* PKt_l = (unsigned short*)(out + (size_t)16891904);   // ends 17,629,184

    const int wtot = NL * 2 * CC * CH * KS;
    k_prep_wbf<<<dim3((wtot + 255) / 256), 256, 0, stream>>>(Win, PKc_h, PKc_l, PKt_h, PKt_l);
    k_prep_bks<<<dim3((NL * 2 * CC * KS + 255) / 256), 256, 0, stream>>>(Win, Bias, bks);
    k_zero<<<dim3(BB * NN / 256), 256, 0, stream>>>(Wsum, BB * NN);
    k_msum<<<dim3(BB), 256, 0, stream>>>(mask, msum);
    k_open<<<dim3(NN / 256, CH, BB), 256, 0, stream>>>(Zin, mask, Kop, Zcur);
    k_za<<<dim3(65, BB), 256, 0, stream>>>(Zcur, mask, Za);
    k_gramW<<<dim3(16, 16, BB), 256, 0, stream>>>(Za, mask, Wpk2, Wsum);

    for (int l = 0; l < NL; ++l) {
        const unsigned short* PKc_h_l = PKc_h + (size_t)l * 2 * CC * 576;
        const unsigned short* PKc_l_l = PKc_l + (size_t)l * 2 * CC * 576;
        const unsigned short* PKt_h_l = PKt_h + (size_t)l * 2 * CH * 1152;
        const unsigned short* PKt_l_l = PKt_l + (size_t)l * 2 * CH * 1152;
        const float* bksl = bks + (size_t)l * 2 * CC * KS;

        k_conv1_mfma<<<dim3(NN / 64, 4, BB), 256, 0, stream>>>(
            Zcur, PKc_h_l, PKc_l_l, bksl, mask, C0, C1, C1pk, meanP0);
        k_matL_cc<<<dim3(NN / 16, 1, BB * 2), 256, 0, stream>>>(
            C1pk, Wpk2, C1, Wsum, mask, A1, meanP1);
        k_convT_mfma<<<dim3(NN / 32, 2, BB), 256, 0, stream>>>(
            C0, A1, PKt_h_l, PKt_l_l, mask, meanP0, meanP1, msum, T0, T1p, T1pk);
        k_matL_ch<<<dim3(NN / 16, 1, BB), 256, 0, stream>>>(
            T1pk, Wpk2, T1p, Wsum, mask, T0, Zcur);
    }

    float* Zout = out + (size_t)BB * 3 * NN * NN;
    k_close<<<dim3(NN / 64, BB), 256, 0, stream>>>(Zcur, Kcl, mask, Zout);
    k_center3<<<dim3(COUT, BB), 256, 0, stream>>>(Zout, Zc3);
    k_dist<<<dim3(16, 16, 3 * BB), 256, 0, stream>>>(Zc3, out);
}

// Round 16
// 774.882 us; speedup vs baseline: 1.0160x; 1.0160x over previous
//
#include <hip/hip_runtime.h>
#include <cstddef>

#define BB 8
#define NN 1024
#define CIN 40
#define CH 64
#define CC 128
#define COUT 9
#define KS 9
#define NL 10
#define HSTEP 0.1f

typedef __attribute__((ext_vector_type(8))) short bf16x8;
typedef __attribute__((ext_vector_type(4))) float f32x4;

__device__ __forceinline__ unsigned short f2bf(float f) {
    union { float f; unsigned u; } v;
    v.f = f;
    unsigned u = v.u;
    u += 0x7FFFu + ((u >> 16) & 1u);
    return (unsigned short)(u >> 16);
}
__device__ __forceinline__ float bf2f(unsigned short h) {
    union { unsigned u; float f; } v;
    v.u = ((unsigned)h) << 16;
    return v.f;
}

// packed-fragment address (chunk = 64 lanes x 8 shorts = 512 shorts):
// chunk=((lb*(R/32)+row>>5)*(KDv/32)+col>>5)*2+((row>>4)&1), lane=((col>>3)&3)*16+(row&15)
__device__ __forceinline__ size_t pk_addr(int lb, int row, int col, int R, int KDv) {
    int chunk = ((lb * (R / 32) + (row >> 5)) * (KDv / 32) + (col >> 5)) * 2 + ((row >> 4) & 1);
    int lane = ((col >> 3) & 3) * 16 + (row & 15);
    return ((size_t)chunk * 64 + lane) * 8 + (col & 7);
}

// ---------------- helpers ----------------
__device__ __forceinline__ float blockSum(float v, float* red) {
    int tid = threadIdx.x;
    red[tid] = v;
    __syncthreads();
    for (int s = 128; s > 0; s >>= 1) {
        if (tid < s) red[tid] += red[tid + s];
        __syncthreads();
    }
    float r = red[0];
    __syncthreads();
    return r;
}

__global__ __launch_bounds__(256) void k_zero(float* __restrict__ p, int n) {
    int i = blockIdx.x * 256 + threadIdx.x;
    if (i < n) p[i] = 0.f;
}

__global__ __launch_bounds__(256) void k_msum(const float* __restrict__ mask,
                                              float* __restrict__ msum) {
    __shared__ float red[256];
    int b = blockIdx.x, tid = threadIdx.x;
    float s = 0.f;
    for (int n = tid; n < NN; n += 256) s += mask[b * NN + n];
    s = blockSum(s, red);
    if (tid == 0) msum[b] = s;
}

// ---------------- conv weights -> packed fragments, k-major contraction, hi/lo ----------------
__global__ __launch_bounds__(256) void k_prep_wbf(const float* __restrict__ Win,
                                                  unsigned short* __restrict__ PKc_h,
                                                  unsigned short* __restrict__ PKc_l,
                                                  unsigned short* __restrict__ PKt_h,
                                                  unsigned short* __restrict__ PKt_l) {
    int idx = blockIdx.x * 256 + threadIdx.x;
    const int total = NL * 2 * CC * CH * KS;
    if (idx >= total) return;
    int k = idx % KS;
    int t = idx / KS;
    int i = t % CH;  t /= CH;
    int o = t % CC;  t /= CC;
    int lb = t;
    float v = Win[idx];
    unsigned short h = f2bf(v);
    unsigned short l = f2bf(v - bf2f(h));
    size_t ac = pk_addr(lb, o, k * 64 + i, CC, 576);
    size_t at = pk_addr(lb, i, (8 - k) * 128 + o, CH, 1152);
    PKc_h[ac] = h;
    PKc_l[ac] = l;
    PKt_h[at] = h;
    PKt_l[at] = l;
}

// bks[lb][o][k] = sum_i Win[lb][o][i][k] * Bias[lb][i]
__global__ __launch_bounds__(256) void k_prep_bks(const float* __restrict__ Win,
                                                  const float* __restrict__ Bias,
                                                  float* __restrict__ bks) {
    int idx = blockIdx.x * 256 + threadIdx.x;
    const int total = NL * 2 * CC * KS;
    if (idx >= total) return;
    int k = idx % KS;
    int t = idx / KS;
    int o = t % CC;
    int lb = t / CC;
    float s = 0.f;
    for (int i = 0; i < CH; ++i)
        s += Win[(((size_t)lb * CC + o) * CH + i) * KS + k] * Bias[lb * CH + i];
    bks[idx] = s;
}

// ---------------- open ----------------
__global__ __launch_bounds__(256) void k_open(const float* __restrict__ Zin,
                                              const float* __restrict__ mask,
                                              const float* __restrict__ Kop,
                                              float* __restrict__ Zcur) {
    int n = blockIdx.x * 256 + threadIdx.x;
    int c = blockIdx.y, b = blockIdx.z;
    float acc = 0.f;
    for (int i = 0; i < CIN; ++i)
        acc += Kop[c * CIN + i] * Zin[((size_t)b * CIN + i) * NN + n];
    Zcur[((size_t)b * CH + c) * NN + n] = acc * mask[b * NN + n];
}

// ---------------- Za ----------------
__global__ __launch_bounds__(256) void k_za(const float* __restrict__ Zcur,
                                            const float* __restrict__ mask,
                                            float* __restrict__ Za) {
    __shared__ float red[256];
    int c = blockIdx.x;  // 0..64
    int b = blockIdx.y;
    int tid = threadIdx.x;
    const float* m = mask + b * NN;
    float x[4], mv[4];
    if (c < CH) {
        const float* src = Zcur + ((size_t)b * CH + c) * NN;
#pragma unroll
        for (int j = 0; j < 4; ++j) { int n = tid * 4 + j; x[j] = src[n]; mv[j] = m[n]; }
    } else {
#pragma unroll
        for (int j = 0; j < 4; ++j) { int n = tid * 4 + j; mv[j] = m[n]; x[j] = 0.5f * ((float)n / 1023.f) * mv[j]; }
    }
    float sm = 0.f, sxm = 0.f;
#pragma unroll
    for (int j = 0; j < 4; ++j) { sm += mv[j]; sxm += x[j] * mv[j]; }
    float msum = blockSum(sm, red);
    float xm = blockSum(sxm, red);
    if (c < CH) {
        float mean = xm / msum;
        float ss = 0.f;
#pragma unroll
        for (int j = 0; j < 4; ++j) { x[j] -= mean * mv[j]; ss += x[j] * x[j]; }
        ss = blockSum(ss, red);
        float sc = rsqrtf(ss / msum + 1e-4f);
#pragma unroll
        for (int j = 0; j < 4; ++j) x[j] *= sc;
    }
    float ps = 0.f;
#pragma unroll
    for (int j = 0; j < 4; ++j) ps += x[j];
    float pm = blockSum(ps, red) / (float)NN;
    float* dst = Za + ((size_t)b * 65 + c) * NN;
#pragma unroll
    for (int j = 0; j < 4; ++j) dst[tid * 4 + j] = x[j] - pm;
}

// ---------------- Gram + W: local n2, writes packed bf16 W + atomic fp32 Wsum ----------------
__global__ __launch_bounds__(256) void k_gramW(const float* __restrict__ Za,
                                               const float* __restrict__ mask,
                                               unsigned short* __restrict__ Wpk,
                                               float* __restrict__ Wsum) {
    __shared__ float As[65][68];
    __shared__ float Bs2[65][68];
    __shared__ unsigned short wt[64][72];
    __shared__ float csred[16][64];
    __shared__ float n2is[64], n2js[64];
    int i0 = blockIdx.x * 64, j0 = blockIdx.y * 64, b = blockIdx.z;
    int tid = threadIdx.x;
    for (int e = tid; e < 65 * 64; e += 256) {
        int c = e >> 6, t = e & 63;
        const float* src = Za + ((size_t)b * 65 + c) * NN;
        As[c][t] = src[i0 + t];
        Bs2[c][t] = src[j0 + t];
    }
    __syncthreads();
    if (tid < 64) {
        float s = 0.f;
        for (int c = 0; c < 65; ++c) { float v = As[c][tid]; s += v * v; }
        n2is[tid] = s;
    } else if (tid < 128) {
        int t = tid - 64;
        float s = 0.f;
        for (int c = 0; c < 65; ++c) { float v = Bs2[c][t]; s += v * v; }
        n2js[t] = s;
    }
    __syncthreads();
    int tx = tid & 15, ty = tid >> 4;
    float acc[4][4] = {};
    for (int c = 0; c < 65; ++c) {
        float a[4];
#pragma unroll
        for (int q = 0; q < 4; ++q) a[q] = As[c][ty * 4 + q];
        float bv[4];
        *reinterpret_cast<float4*>(bv) = *reinterpret_cast<const float4*>(&Bs2[c][tx * 4]);
#pragma unroll
        for (int q = 0; q < 4; ++q)
#pragma unroll
            for (int r = 0; r < 4; ++r) acc[q][r] += a[q] * bv[r];
    }
    const float* m = mask + b * NN;
    float csacc[4] = {0.f, 0.f, 0.f, 0.f};
    for (int q = 0; q < 4; ++q) {
        int i = i0 + ty * 4 + q;
        float n2i = n2is[ty * 4 + q], mi = m[i];
#pragma unroll
        for (int r = 0; r < 4; ++r) {
            int j = j0 + tx * 4 + r;
            float D = n2i + n2js[tx * 4 + r] - 2.f * acc[q][r];
            D *= (3.f / 65.f);
            D = fmaxf(D, 0.f);
            float dist = (D > 0.f) ? sqrtf(D) : 0.f;
            float mmv = mi * m[j];
            float res = expf(-dist * mmv) * mmv;
            wt[ty * 4 + q][tx * 4 + r] = f2bf(res);
            csacc[r] += res;
        }
    }
#pragma unroll
    for (int r = 0; r < 4; ++r) csred[ty][tx * 4 + r] = csacc[r];
    __syncthreads();
    for (int s = 8; s > 0; s >>= 1) {
        if (ty < s) {
#pragma unroll
            for (int r = 0; r < 4; ++r) csred[ty][tx * 4 + r] += csred[ty + s][tx * 4 + r];
        }
        __syncthreads();
    }
    if (ty == 0) {
#pragma unroll
        for (int r = 0; r < 4; ++r)
            atomicAdd(&Wsum[b * NN + j0 + tx * 4 + r], csred[0][tx * 4 + r]);
    }
    for (int e = tid; e < 512; e += 256) {
        int li = e >> 3, ljb = (e & 7) * 8;
        int row = i0 + li, col = j0 + ljb;
        int chunk = ((b * 32 + (row >> 5)) * 32 + (col >> 5)) * 2 + ((row >> 4) & 1);
        int lane2 = ((col >> 3) & 3) * 16 + (row & 15);
        unsigned short* dp = Wpk + ((size_t)chunk * 64 + lane2) * 8;
        *reinterpret_cast<ushort4*>(dp) = *reinterpret_cast<ushort4*>(&wt[li][ljb]);
        *reinterpret_cast<ushort4*>(dp + 4) = *reinterpret_cast<ushort4*>(&wt[li][ljb + 4]);
    }
}

// ---------------- conv1 (k-major MFMA): block 64o x 64n, y=(br,o_half) ----------------
// br==0 emits meanP0[b][c][nt16] masked row-partials; br==1 emits C1pk packed bf16.
__global__ __launch_bounds__(256) void k_conv1_mfma(const float* __restrict__ Zcur,
                                                    const unsigned short* __restrict__ Wh,
                                                    const unsigned short* __restrict__ Wl,
                                                    const float* __restrict__ bksl,
                                                    const float* __restrict__ mask,
                                                    float* __restrict__ C0,
                                                    float* __restrict__ C1,
                                                    unsigned short* __restrict__ C1pk,
                                                    float* __restrict__ meanP0) {
    __shared__ __align__(16) unsigned short xh[80][64];
    __shared__ __align__(16) unsigned short xl[80][64];
    __shared__ float rs[64][2];
    int n0 = blockIdx.x * 64;
    int y = blockIdx.y;
    int b = blockIdx.z;
    int br = y >> 1, half = y & 1;
    int tid = threadIdx.x;
    const float* Xb = Zcur + (size_t)b * CH * NN;

    for (int e = tid; e < 64 * 20; e += 256) {
        int i = e / 20, t = e - i * 20;
        int gn = n0 + t * 4 - 4;
        float4 v = make_float4(0.f, 0.f, 0.f, 0.f);
        if (gn >= 0 && gn + 3 < NN) v = *reinterpret_cast<const float4*>(&Xb[(size_t)i * NN + gn]);
        float vv[4] = {v.x, v.y, v.z, v.w};
#pragma unroll
        for (int j = 0; j < 4; ++j) {
            int row = t * 4 + j;
            int col = i ^ ((row & 7) << 3);
            unsigned short h = f2bf(vv[j]);
            xh[row][col] = h;
            xl[row][col] = f2bf(vv[j] - bf2f(h));
        }
    }
    __syncthreads();

    int wid = tid >> 6, lane = tid & 63;
    int wo = (wid >> 1) * 32, wn = (wid & 1) * 32;
    int r = lane & 15, g = lane >> 4;
    int r32 = half * 2 + (wid >> 1);
    size_t brOff = (size_t)br * (CC / 32) * (576 / 32) * 1024;

    f32x4 acc[2][2] = {};
#pragma unroll 3
    for (int q = 0; q < 18; ++q) {
        int k = q >> 1, s = q & 1;
        size_t widx = brOff + ((size_t)(r32 * 18 + q)) * 1024 + lane * 8;
        bf16x8 ah[2], al[2];
        ah[0] = *reinterpret_cast<const bf16x8*>(&Wh[widx]);
        ah[1] = *reinterpret_cast<const bf16x8*>(&Wh[widx + 512]);
        al[0] = *reinterpret_cast<const bf16x8*>(&Wl[widx]);
        al[1] = *reinterpret_cast<const bf16x8*>(&Wl[widx + 512]);
        bf16x8 bh[2], bl[2];
#pragma unroll
        for (int fn = 0; fn < 2; ++fn) {
            int row = wn + fn * 16 + r + k;
            int chs = (s * 32 + g * 8) ^ ((row & 7) << 3);
            bh[fn] = *reinterpret_cast<const bf16x8*>(&xh[row][chs]);
            bl[fn] = *reinterpret_cast<const bf16x8*>(&xl[row][chs]);
        }
#pragma unroll
        for (int fc = 0; fc < 2; ++fc)
#pragma unroll
            for (int fn = 0; fn < 2; ++fn) {
                acc[fc][fn] = __builtin_amdgcn_mfma_f32_16x16x32_bf16(ah[fc], bh[fn], acc[fc][fn], 0, 0, 0);
                acc[fc][fn] = __builtin_amdgcn_mfma_f32_16x16x32_bf16(al[fc], bh[fn], acc[fc][fn], 0, 0, 0);
                acc[fc][fn] = __builtin_amdgcn_mfma_f32_16x16x32_bf16(ah[fc], bl[fn], acc[fc][fn], 0, 0, 0);
            }
    }

    const float* mkB = mask + b * NN;
    float* Outp = (br ? C1 : C0) + ((size_t)b * CC + half * 64) * NN;
    const float* bo_base = bksl + (br * CC + half * 64) * KS;
    float p[2][4] = {};
#pragma unroll
    for (int fc = 0; fc < 2; ++fc) {
#pragma unroll
        for (int fn = 0; fn < 2; ++fn) {
            int n = n0 + wn + fn * 16 + r;
#pragma unroll
            for (int rr = 0; rr < 4; ++rr) {
                int oo = wo + fc * 16 + 4 * g + rr;
                float v = acc[fc][fn][rr];
                const float* bo = bo_base + oo * KS;
                float bias = 0.f;
#pragma unroll
                for (int k = 0; k < KS; ++k) {
                    int nn2 = n + k - 4;
                    if (nn2 >= 0 && nn2 < NN) bias += bo[k];
                }
                v += bias;
                if (br == 0) {
                    v *= mkB[n];
                    p[fc][rr] += v * mkB[n];
                }
                Outp[(size_t)oo * NN + n] = v;
                if (br == 1) {
                    int cg = half * 64 + oo;
                    int chunk = ((b * 4 + (cg >> 5)) * 32 + (n >> 5)) * 2 + ((cg >> 4) & 1);
                    int lane2 = ((n >> 3) & 3) * 16 + (cg & 15);
                    C1pk[((size_t)chunk * 64 + lane2) * 8 + (n & 7)] = f2bf(v);
                }
            }
        }
    }
    if (br == 0) {
#pragma unroll
        for (int fc = 0; fc < 2; ++fc)
#pragma unroll
            for (int rr = 0; rr < 4; ++rr) {
                float v = p[fc][rr];
                v += __shfl_xor(v, 1); v += __shfl_xor(v, 2);
                v += __shfl_xor(v, 4); v += __shfl_xor(v, 8);
                if (r == 0) rs[wo + fc * 16 + 4 * g + rr][wid & 1] = v;
            }
        __syncthreads();
        if (tid < 64)
            meanP0[((size_t)b * CC + half * 64 + tid) * 16 + blockIdx.x] = rs[tid][0] + rs[tid][1];
    }
}

// ---------------- fused CC matL: Y=C1@L epilogue in-kernel ----------------
// grid (NN/32, 1, BB*2); block 64c x 32n; waves: kh=wid>>1 K-half, ch=wid&1 c-half.
// A1 = (C1*Wsum - acc)*mask ; emits meanP1[b][c][nt32] masked row-partials.
__global__ __launch_bounds__(256) void k_matL_cc(const unsigned short* __restrict__ C1pk,
                                                 const unsigned short* __restrict__ Wpk,
                                                 const float* __restrict__ C1,
                                                 const float* __restrict__ Wsum,
                                                 const float* __restrict__ mask,
                                                 float* __restrict__ A1,
                                                 float* __restrict__ meanP1) {
    __shared__ float red2[2][32][33];
    int nt32 = blockIdx.x;
    int b = blockIdx.z >> 1, chalf = blockIdx.z & 1;
    int c0 = chalf * 64;
    int tid = threadIdx.x;
    int wid = tid >> 6, lane = tid & 63;
    int kh = wid >> 1, ch = wid & 1;
    int r = lane & 15, g = lane >> 4;
    int ct = chalf * 2 + ch;
    const unsigned short* Xb = C1pk + ((size_t)(b * 4 + ct)) * 32768 + (size_t)lane * 8;
    const unsigned short* Wb = Wpk + ((size_t)(b * 32 + nt32)) * 32768 + (size_t)lane * 8;

    f32x4 acc[2][2] = {};
#pragma unroll 4
    for (int ms = kh * 16; ms < kh * 16 + 16; ++ms) {
        bf16x8 a0 = *reinterpret_cast<const bf16x8*>(&Xb[(size_t)ms * 1024]);
        bf16x8 a1 = *reinterpret_cast<const bf16x8*>(&Xb[(size_t)ms * 1024 + 512]);
        bf16x8 w0 = *reinterpret_cast<const bf16x8*>(&Wb[(size_t)ms * 1024]);
        bf16x8 w1 = *reinterpret_cast<const bf16x8*>(&Wb[(size_t)ms * 1024 + 512]);
        acc[0][0] = __builtin_amdgcn_mfma_f32_16x16x32_bf16(a0, w0, acc[0][0], 0, 0, 0);
        acc[0][1] = __builtin_amdgcn_mfma_f32_16x16x32_bf16(a0, w1, acc[0][1], 0, 0, 0);
        acc[1][0] = __builtin_amdgcn_mfma_f32_16x16x32_bf16(a1, w0, acc[1][0], 0, 0, 0);
        acc[1][1] = __builtin_amdgcn_mfma_f32_16x16x32_bf16(a1, w1, acc[1][1], 0, 0, 0);
    }
    if (kh == 1) {
#pragma unroll
        for (int fc = 0; fc < 2; ++fc)
#pragma unroll
            for (int fn = 0; fn < 2; ++fn)
#pragma unroll
                for (int rr = 0; rr < 4; ++rr)
                    red2[ch][fc * 16 + 4 * g + rr][fn * 16 + r] = acc[fc][fn][rr];
    }
    __syncthreads();
    if (kh == 0) {
        const float* C1b = C1 + (size_t)b * CC * NN;
        float* A1b = A1 + (size_t)b * CC * NN;
        const float* mk = mask + b * NN;
        const float* wsB = Wsum + b * NN;
        float p[2][4] = {};
#pragma unroll
        for (int fc = 0; fc < 2; ++fc)
#pragma unroll
            for (int fn = 0; fn < 2; ++fn) {
                int ncol = nt32 * 32 + fn * 16 + r;
                float mkv = mk[ncol], wsv = wsB[ncol];
#pragma unroll
                for (int rr = 0; rr < 4; ++rr) {
                    int crow = c0 + ch * 32 + fc * 16 + 4 * g + rr;
                    float v = acc[fc][fn][rr] + red2[ch][fc * 16 + 4 * g + rr][fn * 16 + r];
                    float y = C1b[(size_t)crow * NN + ncol] * wsv - v;
                    float res = y * mkv;
                    A1b[(size_t)crow * NN + ncol] = res;
                    p[fc][rr] += res * mkv;
                }
            }
#pragma unroll
        for (int fc = 0; fc < 2; ++fc)
#pragma unroll
            for (int rr = 0; rr < 4; ++rr) {
                float v = p[fc][rr];
                v += __shfl_xor(v, 1); v += __shfl_xor(v, 2);
                v += __shfl_xor(v, 4); v += __shfl_xor(v, 8);
                if (r == 0)
                    meanP1[((size_t)b * CC + c0 + ch * 32 + fc * 16 + 4 * g + rr) * 32 + nt32] = v;
            }
    }
}

// ---------------- conv1T (k-major MFMA): block 64i x 32n, y=br; in-block split-K ----------------
// Colnorm fully local; meanA assembled from meanP0/meanP1 partials + msum.
// br==1 additionally writes T1p packed bf16.
__global__ __launch_bounds__(256) void k_convT_mfma(const float* __restrict__ C0,
                                                    const float* __restrict__ A1,
                                                    const unsigned short* __restrict__ Wh,
                                                    const unsigned short* __restrict__ Wl,
                                                    const float* __restrict__ mask,
                                                    const float* __restrict__ meanP0,
                                                    const float* __restrict__ meanP1,
                                                    const float* __restrict__ msum,
                                                    float* __restrict__ T0,
                                                    float* __restrict__ T1p,
                                                    unsigned short* __restrict__ T1pk) {
    __shared__ float fs[48][132];
    __shared__ __align__(16) unsigned short xh[48][128];
    __shared__ __align__(16) unsigned short xl[48][128];
    __shared__ float red2[2][32][33];
    __shared__ float ps[48][4];
    __shared__ float invc[48];
    __shared__ float meB_sh[128];
    int n0 = blockIdx.x * 32;
    int br = blockIdx.y;
    int b = blockIdx.z;
    int tid = threadIdx.x;
    const float* Xb = (br ? A1 : C0) + (size_t)b * CC * NN;
    const float* mkB = mask + b * NN;

    if (tid < 128) {
        float s = 0.f;
        if (br == 0) {
            const float* mp = meanP0 + ((size_t)b * CC + tid) * 16;
#pragma unroll
            for (int t = 0; t < 16; ++t) s += mp[t];
        } else {
            const float* mp = meanP1 + ((size_t)b * CC + tid) * 32;
#pragma unroll
            for (int t = 0; t < 32; ++t) s += mp[t];
        }
        meB_sh[tid] = s / msum[b];
    }
    __syncthreads();

    // pass 1: stage raw (x - mean)*mask (fp32)
    for (int e = tid; e < 128 * 12; e += 256) {
        int i = e / 12, t = e - i * 12;
        int gn = n0 + t * 4 - 4;
        float4 v = make_float4(0.f, 0.f, 0.f, 0.f);
        if (gn >= 0 && gn + 3 < NN) {
            v = *reinterpret_cast<const float4*>(&Xb[(size_t)i * NN + gn]);
            float me = meB_sh[i];
            float4 mk = *reinterpret_cast<const float4*>(&mkB[gn]);
            v.x = (v.x - me) * mk.x;
            v.y = (v.y - me) * mk.y;
            v.z = (v.z - me) * mk.z;
            v.w = (v.w - me) * mk.w;
        }
        fs[t * 4 + 0][i] = v.x;
        fs[t * 4 + 1][i] = v.y;
        fs[t * 4 + 2][i] = v.z;
        fs[t * 4 + 3][i] = v.w;
    }
    __syncthreads();
    // pass 2: per-column sums over 128 channels -> inv
    if (tid < 192) {
        int row = tid % 48, seg = tid / 48;
        float ss = 0.f;
#pragma unroll
        for (int i = 0; i < 32; ++i) { float v = fs[row][seg * 32 + i]; ss += v * v; }
        ps[row][seg] = ss;
    }
    __syncthreads();
    if (tid < 48) invc[tid] = rsqrtf(ps[tid][0] + ps[tid][1] + ps[tid][2] + ps[tid][3] + 0.001f);
    __syncthreads();
    // pass 3: relu(v*inv), hi/lo pack with XOR swizzle
    for (int e = tid; e < 128 * 12; e += 256) {
        int i = e / 12, t = e - i * 12;
#pragma unroll
        for (int j = 0; j < 4; ++j) {
            int row = t * 4 + j;
            float v = fmaxf(fs[row][i] * invc[row], 0.f);
            int col = i ^ ((row & 7) << 3);
            unsigned short h = f2bf(v);
            xh[row][col] = h;
            xl[row][col] = f2bf(v - bf2f(h));
        }
    }
    __syncthreads();

    int wid = tid >> 6, lane = tid & 63;
    int i32 = wid & 1, kh = wid >> 1;
    int r = lane & 15, g = lane >> 4;
    size_t brW = (size_t)br * (CH / 32) * (1152 / 32) * 1024;

    f32x4 acc[2][2] = {};
#pragma unroll 3
    for (int t = 0; t < 18; ++t) {
        int k = t >> 1, s = kh * 2 + (t & 1);
        int q32 = k * 4 + s;
        size_t widx = brW + ((size_t)(i32 * 36 + q32)) * 1024 + lane * 8;
        bf16x8 ah[2], al[2];
        ah[0] = *reinterpret_cast<const bf16x8*>(&Wh[widx]);
        ah[1] = *reinterpret_cast<const bf16x8*>(&Wh[widx + 512]);
        al[0] = *reinterpret_cast<const bf16x8*>(&Wl[widx]);
        al[1] = *reinterpret_cast<const bf16x8*>(&Wl[widx + 512]);
        bf16x8 bh[2], bl[2];
#pragma unroll
        for (int fn = 0; fn < 2; ++fn) {
            int row = fn * 16 + r + k;
            int chs = (s * 32 + g * 8) ^ ((row & 7) << 3);
            bh[fn] = *reinterpret_cast<const bf16x8*>(&xh[row][chs]);
            bl[fn] = *reinterpret_cast<const bf16x8*>(&xl[row][chs]);
        }
#pragma unroll
        for (int fc = 0; fc < 2; ++fc)
#pragma unroll
            for (int fn = 0; fn < 2; ++fn) {
                acc[fc][fn] = __builtin_amdgcn_mfma_f32_16x16x32_bf16(ah[fc], bh[fn], acc[fc][fn], 0, 0, 0);
                acc[fc][fn] = __builtin_amdgcn_mfma_f32_16x16x32_bf16(al[fc], bh[fn], acc[fc][fn], 0, 0, 0);
                acc[fc][fn] = __builtin_amdgcn_mfma_f32_16x16x32_bf16(ah[fc], bl[fn], acc[fc][fn], 0, 0, 0);
            }
    }

    if (kh == 1) {
#pragma unroll
        for (int fc = 0; fc < 2; ++fc)
#pragma unroll
            for (int fn = 0; fn < 2; ++fn)
#pragma unroll
                for (int rr = 0; rr < 4; ++rr)
                    red2[i32][fc * 16 + 4 * g + rr][fn * 16 + r] = acc[fc][fn][rr];
    }
    __syncthreads();
    if (kh == 0) {
        float* Outp = (br ? T1p : T0) + (size_t)b * CH * NN;
#pragma unroll
        for (int fc = 0; fc < 2; ++fc)
#pragma unroll
            for (int fn = 0; fn < 2; ++fn) {
                int n = n0 + fn * 16 + r;
#pragma unroll
                for (int rr = 0; rr < 4; ++rr) {
                    int irow = fc * 16 + 4 * g + rr;
                    float v = acc[fc][fn][rr] + red2[i32][irow][fn * 16 + r];
                    Outp[(size_t)(i32 * 32 + irow) * NN + n] = v;
                    if (br == 1) {
                        int cg = i32 * 32 + irow;
                        int chunk = ((b * 2 + (cg >> 5)) * 32 + (n >> 5)) * 2 + ((cg >> 4) & 1);
                        int lane2 = ((n >> 3) & 3) * 16 + (cg & 15);
                        T1pk[((size_t)chunk * 64 + lane2) * 8 + (n & 7)] = f2bf(v);
                    }
                }
            }
    }
}

// ---------------- fused CH matL: Zcur -= H*mask*(T0 + T1p@L) ----------------
// grid (NN/32, 1, BB); block 64c x 32n; waves: kh x c-half.
__global__ __launch_bounds__(256) void k_matL_ch(const unsigned short* __restrict__ T1pk,
                                                 const unsigned short* __restrict__ Wpk,
                                                 const float* __restrict__ T1p,
                                                 const float* __restrict__ Wsum,
                                                 const float* __restrict__ mask,
                                                 const float* __restrict__ T0,
                                                 float* __restrict__ Zcur) {
    __shared__ float red2[2][32][33];
    int nt32 = blockIdx.x;
    int b = blockIdx.z;
    int tid = threadIdx.x;
    int wid = tid >> 6, lane = tid & 63;
    int kh = wid >> 1, ch = wid & 1;
    int r = lane & 15, g = lane >> 4;
    const unsigned short* Xb = T1pk + ((size_t)(b * 2 + ch)) * 32768 + (size_t)lane * 8;
    const unsigned short* Wb = Wpk + ((size_t)(b * 32 + nt32)) * 32768 + (size_t)lane * 8;

    f32x4 acc[2][2] = {};
#pragma unroll 4
    for (int ms = kh * 16; ms < kh * 16 + 16; ++ms) {
        bf16x8 a0 = *reinterpret_cast<const bf16x8*>(&Xb[(size_t)ms * 1024]);
        bf16x8 a1 = *reinterpret_cast<const bf16x8*>(&Xb[(size_t)ms * 1024 + 512]);
        bf16x8 w0 = *reinterpret_cast<const bf16x8*>(&Wb[(size_t)ms * 1024]);
        bf16x8 w1 = *reinterpret_cast<const bf16x8*>(&Wb[(size_t)ms * 1024 + 512]);
        acc[0][0] = __builtin_amdgcn_mfma_f32_16x16x32_bf16(a0, w0, acc[0][0], 0, 0, 0);
        acc[0][1] = __builtin_amdgcn_mfma_f32_16x16x32_bf16(a0, w1, acc[0][1], 0, 0, 0);
        acc[1][0] = __builtin_amdgcn_mfma_f32_16x16x32_bf16(a1, w0, acc[1][0], 0, 0, 0);
        acc[1][1] = __builtin_amdgcn_mfma_f32_16x16x32_bf16(a1, w1, acc[1][1], 0, 0, 0);
    }
    if (kh == 1) {
#pragma unroll
        for (int fc = 0; fc < 2; ++fc)
#pragma unroll
            for (int fn = 0; fn < 2; ++fn)
#pragma unroll
                for (int rr = 0; rr < 4; ++rr)
                    red2[ch][fc * 16 + 4 * g + rr][fn * 16 + r] = acc[fc][fn][rr];
    }
    __syncthreads();
    if (kh == 0) {
        const float* T1b = T1p + (size_t)b * CH * NN;
        const float* T0b = T0 + (size_t)b * CH * NN;
        float* Zb = Zcur + (size_t)b * CH * NN;
        const float* mk = mask + b * NN;
        const float* wsB = Wsum + b * NN;
#pragma unroll
        for (int fc = 0; fc < 2; ++fc)
#pragma unroll
            for (int fn = 0; fn < 2; ++fn) {
                int ncol = nt32 * 32 + fn * 16 + r;
                float mkv = mk[ncol], wsv = wsB[ncol];
#pragma unroll
                for (int rr = 0; rr < 4; ++rr) {
                    int crow = ch * 32 + fc * 16 + 4 * g + rr;
                    float v = acc[fc][fn][rr] + red2[ch][fc * 16 + 4 * g + rr][fn * 16 + r];
                    float y = T1b[(size_t)crow * NN + ncol] * wsv - v;
                    size_t zi = (size_t)crow * NN + ncol;
                    Zb[zi] = Zb[zi] - HSTEP * mkv * (T0b[zi] + y);
                }
            }
    }
}

// ---------------- close ----------------
__global__ __launch_bounds__(256) void k_close(const float* __restrict__ Zcur,
                                               const float* __restrict__ Kcl,
                                               const float* __restrict__ mask,
                                               float* __restrict__ Zout) {
    __shared__ float red[4][64][COUT];
    int tid = threadIdx.x;
    int nl = tid & 63, cg = tid >> 6;
    int n = blockIdx.x * 64 + nl;
    int b = blockIdx.y;
    float acc[COUT] = {};
#pragma unroll
    for (int cc = 0; cc < 16; ++cc) {
        int c = cg * 16 + cc;
        float zv = Zcur[((size_t)b * CH + c) * NN + n];
#pragma unroll
        for (int o = 0; o < COUT; ++o) acc[o] += Kcl[o * CH + c] * zv;
    }
#pragma unroll
    for (int o = 0; o < COUT; ++o) red[cg][nl][o] = acc[o];
    __syncthreads();
    if (cg == 0) {
        float mv = mask[b * NN + n];
#pragma unroll
        for (int o = 0; o < COUT; ++o) {
            float s = red[0][nl][o] + red[1][nl][o] + red[2][nl][o] + red[3][nl][o];
            Zout[((size_t)b * COUT + o) * NN + n] = s * mv;
        }
    }
}

// ---------------- center3 ----------------
__global__ __launch_bounds__(256) void k_center3(const float* __restrict__ Zout, float* __restrict__ Zc3) {
    __shared__ float red[256];
    int c = blockIdx.x, b = blockIdx.y, tid = threadIdx.x;
    const float* src = Zout + ((size_t)b * COUT + c) * NN;
    float s = 0.f;
    for (int n = tid; n < NN; n += 256) s += src[n];
    float mean = blockSum(s, red) / (float)NN;
    float* dst = Zc3 + ((size_t)b * COUT + c) * NN;
    for (int n = tid; n < NN; n += 256) dst[n] = src[n] - mean;
}

// ---------------- final pairwise distances ----------------
__global__ __launch_bounds__(256) void k_dist(const float* __restrict__ Zc3,
                                              float* __restrict__ dout) {
    __shared__ float Ai[3][64], Aj[3][64], ni[64], nj[64];
    int bg = blockIdx.z;
    int b = bg / 3, g = bg - 3 * b;
    int i0 = blockIdx.x * 64, j0 = blockIdx.y * 64;
    int tid = threadIdx.x;
    for (int e = tid; e < 192; e += 256) {
        int c = e / 64, t = e - c * 64;
        Ai[c][t] = Zc3[((size_t)b * COUT + g * 3 + c) * NN + i0 + t];
    }
    for (int e = tid; e < 192; e += 256) {
        int c = e / 64, t = e - c * 64;
        Aj[c][t] = Zc3[((size_t)b * COUT + g * 3 + c) * NN + j0 + t];
    }
    __syncthreads();
    if (tid < 64) {
        ni[tid] = Ai[0][tid] * Ai[0][tid] + Ai[1][tid] * Ai[1][tid] + Ai[2][tid] * Ai[2][tid];
    } else if (tid < 128) {
        int t = tid - 64;
        nj[t] = Aj[0][t] * Aj[0][t] + Aj[1][t] * Aj[1][t] + Aj[2][t] * Aj[2][t];
    }
    __syncthreads();
    int tx = tid & 15, ty = tid >> 4;
    for (int q = 0; q < 4; ++q) {
        int i = ty * 4 + q;
        float a0 = Ai[0][i], a1 = Ai[1][i], a2 = Ai[2][i], n2i = ni[i];
        float res[4];
#pragma unroll
        for (int r = 0; r < 4; ++r) {
            int j = tx * 4 + r;
            float D = n2i + nj[j] - 2.f * (a0 * Aj[0][j] + a1 * Aj[1][j] + a2 * Aj[2][j]);
            D = fmaxf(D, 0.f);
            res[r] = (D > 0.f) ? sqrtf(D) : 0.f;
        }
        *reinterpret_cast<float4*>(&dout[(((size_t)b * 3 + g) * NN + i0 + i) * NN + j0 + tx * 4]) =
            *reinterpret_cast<float4*>(res);
    }
}

// ---------------- driver ----------------
extern "C" void kernel_launch(void* const* d_in, const int* in_sizes, int n_in,
                              void* d_out, int out_size, void* d_ws, size_t ws_size,
                              hipStream_t stream) {
    (void)in_sizes; (void)n_in; (void)out_size; (void)ws_size;
    const float* Zin  = (const float*)d_in[0];
    const float* mask = (const float*)d_in[1];
    const float* Kop  = (const float*)d_in[2];
    const float* Kcl  = (const float*)d_in[3];
    const float* Win  = (const float*)d_in[4];
    const float* Bias = (const float*)d_in[5];
    float* out = (float*)d_out;
    float* ws = (float*)d_ws;

    size_t off = 0;
    float* Zcur = ws + off;  off += (size_t)BB * CH * NN;
    float* C0   = ws + off;  off += (size_t)BB * CC * NN;
    float* C1   = ws + off;  off += (size_t)BB * CC * NN;
    float* A1   = ws + off;  off += (size_t)BB * CC * NN;
    float* T0   = ws + off;  off += (size_t)BB * CH * NN;
    float* T1p  = ws + off;  off += (size_t)BB * CH * NN;
    float* Za   = ws + off;  off += (size_t)BB * 65 * NN;
    float* Wsum = ws + off;  off += (size_t)BB * NN;
    float* bks  = ws + off;  off += (size_t)NL * 2 * CC * KS;
    float* Zc3  = ws + off;  off += (size_t)BB * COUT * NN;
    float* meanP0 = ws + off; off += (size_t)BB * CC * 16;
    float* meanP1 = ws + off; off += (size_t)BB * CC * 32;
    float* msum = ws + off;  off += (size_t)BB;

    // Scratch in the (as-yet-unwritten) dists region of d_out (25,165,824 floats):
    unsigned short* Wpk2  = (unsigned short*)(out + (size_t)4194304);    // [.. 8,388,608)
    unsigned short* C1pk  = (unsigned short*)(out + (size_t)8388608);    // 1,048,576 shorts
    unsigned short* T1pk  = (unsigned short*)(out + (size_t)8912896);    // 524,288 shorts
    unsigned short* PKc_h = (unsigned short*)(out + (size_t)14680064);
    unsigned short* PKc_l = (unsigned short*)(out + (size_t)15417344);
    unsigned short* PKt_h = (unsigned short*)(out + (size_t)16154624);
    unsigned short* PKt_l = (unsigned short*)(out + (size_t)16891904);   // ends 17,629,184

    const int wtot = NL * 2 * CC * CH * KS;
    k_prep_wbf<<<dim3((wtot + 255) / 256), 256, 0, stream>>>(Win, PKc_h, PKc_l, PKt_h, PKt_l);
    k_prep_bks<<<dim3((NL * 2 * CC * KS + 255) / 256), 256, 0, stream>>>(Win, Bias, bks);
    k_zero<<<dim3(BB * NN / 256), 256, 0, stream>>>(Wsum, BB * NN);
    k_msum<<<dim3(BB), 256, 0, stream>>>(mask, msum);
    k_open<<<dim3(NN / 256, CH, BB), 256, 0, stream>>>(Zin, mask, Kop, Zcur);
    k_za<<<dim3(65, BB), 256, 0, stream>>>(Zcur, mask, Za);
    k_gramW<<<dim3(16, 16, BB), 256, 0, stream>>>(Za, mask, Wpk2, Wsum);

    for (int l = 0; l < NL; ++l) {
        const unsigned short* PKc_h_l = PKc_h + (size_t)l * 2 * CC * 576;
        const unsigned short* PKc_l_l = PKc_l + (size_t)l * 2 * CC * 576;
        const unsigned short* PKt_h_l = PKt_h + (size_t)l * 2 * CH * 1152;
        const unsigned short* PKt_l_l = PKt_l + (size_t)l * 2 * CH * 1152;
        const float* bksl = bks + (size_t)l * 2 * CC * KS;

        k_conv1_mfma<<<dim3(NN / 64, 4, BB), 256, 0, stream>>>(
            Zcur, PKc_h_l, PKc_l_l, bksl, mask, C0, C1, C1pk, meanP0);
        k_matL_cc<<<dim3(NN / 32, 1, BB * 2), 256, 0, stream>>>(
            C1pk, Wpk2, C1, Wsum, mask, A1, meanP1);
        k_convT_mfma<<<dim3(NN / 32, 2, BB), 256, 0, stream>>>(
            C0, A1, PKt_h_l, PKt_l_l, mask, meanP0, meanP1, msum, T0, T1p, T1pk);
        k_matL_ch<<<dim3(NN / 32, 1, BB), 256, 0, stream>>>(
            T1pk, Wpk2, T1p, Wsum, mask, T0, Zcur);
    }

    float* Zout = out + (size_t)BB * 3 * NN * NN;
    k_close<<<dim3(NN / 64, BB), 256, 0, stream>>>(Zcur, Kcl, mask, Zout);
    k_center3<<<dim3(COUT, BB), 256, 0, stream>>>(Zout, Zc3);
    k_dist<<<dim3(16, 16, 3 * BB), 256, 0, stream>>>(Zc3, out);
}